// Round 1
// baseline (960.020 us; speedup 1.0000x reference)
//
#include <hip/hip_runtime.h>
#include <hip/hip_bf16.h>

#define D_DIM 256
#define EPS_BN 1e-6f
#define EPS_SM 1e-8f

typedef __bf16 bf16x8 __attribute__((ext_vector_type(8)));
typedef __bf16 bf16x4 __attribute__((ext_vector_type(4)));
typedef float  f32x4  __attribute__((ext_vector_type(4)));

__device__ __forceinline__ float wave_reduce_sum(float v) {
    #pragma unroll
    for (int off = 1; off < 64; off <<= 1) v += __shfl_xor(v, off);
    return v;
}

__device__ __forceinline__ float wave_reduce_max(float v) {
    #pragma unroll
    for (int off = 1; off < 64; off <<= 1) v = fmaxf(v, __shfl_xor(v, off));
    return v;
}

__device__ __forceinline__ float sigmoidf_(float x) {
    return 1.0f / (1.0f + __expf(-x));
}

__device__ __forceinline__ void cvt_region(const float* __restrict__ s,
                                           __bf16* __restrict__ d,
                                           int n4, int idx, int stride) {
    const float4* s4 = (const float4*)s;
    bf16x4* d4 = (bf16x4*)d;
    for (int i = idx; i < n4; i += stride) {
        float4 v = s4[i];
        bf16x4 o;
        o[0] = (__bf16)v.x; o[1] = (__bf16)v.y; o[2] = (__bf16)v.z; o[3] = (__bf16)v.w;
        d4[i] = o;
    }
}

// ---------------------------------------------------------------------------
// K0: bf16 conversions (weights + superatom) + cvec[m] = dot(w1, superatom[m]) + b
// Wave-per-row over superatom (conversion + dot in one read), grid-stride for
// the weight regions.
// ---------------------------------------------------------------------------
__global__ __launch_bounds__(256) void k0_convert(
    const float* __restrict__ superatom, __bf16* __restrict__ sup_bf, int M,
    const float* __restrict__ align_w,   const float* __restrict__ align_b,
    float* __restrict__ cvec,
    const float* __restrict__ attend_w,  __bf16* __restrict__ aw_bf,  int n_aw,
    const float* __restrict__ wih,       __bf16* __restrict__ wih_bf, int n_wih,
    const float* __restrict__ whh,       __bf16* __restrict__ whh_bf, int n_whh)
{
    const int tid  = threadIdx.x;
    const int lane = tid & 63;
    const int gw   = (blockIdx.x * 256 + tid) >> 6;
    const int nw   = (gridDim.x * 256) >> 6;

    const float4 w1 = ((const float4*)align_w)[lane];
    const float  b0 = align_b[0];

    for (int m = gw; m < M; m += nw) {
        float4 s = ((const float4*)(superatom + (size_t)m * D_DIM))[lane];
        bf16x4 o;
        o[0] = (__bf16)s.x; o[1] = (__bf16)s.y; o[2] = (__bf16)s.z; o[3] = (__bf16)s.w;
        ((bf16x4*)sup_bf)[(size_t)m * 64 + lane] = o;
        float p = s.x * w1.x + s.y * w1.y + s.z * w1.z + s.w * w1.w;
        p = wave_reduce_sum(p);
        if (lane == 0) cvec[m] = p + b0;
    }

    const int idx    = blockIdx.x * 256 + tid;
    const int stride = gridDim.x * 256;
    cvt_region(attend_w, aw_bf,  n_aw / 4,  idx, stride);
    cvt_region(wih,      wih_bf, n_wih / 4, idx, stride);
    cvt_region(whh,      whh_bf, n_whh / 4, idx, stride);
}

// ---------------------------------------------------------------------------
// K1a: raw scores for all atoms (wave-per-row GEMV, grid-stride) + segment
// boundary scatter into seg_start[M+1]. 8192 waves fully resident -> the
// per-row shfl reduce is latency-hidden; kernel is HBM-BW-bound on atom.
// ---------------------------------------------------------------------------
__global__ __launch_bounds__(256) void k1_score(
    const float* __restrict__ atom,
    const int*   __restrict__ mol_index,
    const float* __restrict__ align_w,   // w2 = align_w + D
    const float* __restrict__ cvec,
    float* __restrict__ att_out,         // [N] raw leaky scores
    int*   __restrict__ seg_start,       // [M+1]
    int N, int M)
{
    const int lane = threadIdx.x & 63;
    const int gw   = (blockIdx.x * 256 + threadIdx.x) >> 6;
    const int nw   = (gridDim.x * 256) >> 6;

    const float4 wa = ((const float4*)(align_w + D_DIM))[lane];

    for (int r = gw; r < N; r += nw) {
        float4 a = ((const float4*)(atom + (size_t)r * D_DIM))[lane];
        float p = a.x * wa.x + a.y * wa.y + a.z * wa.z + a.w * wa.w;
        p = wave_reduce_sum(p);
        const int m = mol_index[r];            // uniform broadcast load
        float sc = cvec[m] + p;
        sc = sc > 0.0f ? sc : 0.01f * sc;      // leaky_relu(0.01)
        if (lane == 0) {
            att_out[r] = sc;
            if (r == 0) {
                for (int mm = 0; mm <= m; ++mm) seg_start[mm] = 0;
            } else {
                const int mp = mol_index[r - 1];
                if (mp != m)
                    for (int mm = mp + 1; mm <= m; ++mm) seg_start[mm] = r;
            }
            if (r == N - 1) {
                for (int mm = m + 1; mm <= M; ++mm) seg_start[mm] = N;
            }
        }
    }
}

// ---------------------------------------------------------------------------
// K1b: wave-per-molecule. Softmax stats from the score vector (L2-hot),
// then zero-cross-lane weighted streaming accumulation of atom rows.
// Writes final attention weights in place, ctxwn (bf16) and wsum.
// ---------------------------------------------------------------------------
__global__ __launch_bounds__(256) void k1_ctx(
    const float* __restrict__ atom,
    const int*   __restrict__ seg_start,
    float* __restrict__ att,             // in: raw scores; out: final weights
    __bf16* __restrict__ ctxwn_bf,       // [M, D]
    float* __restrict__ wsum)            // [M]
{
    const int lane = threadIdx.x & 63;
    const int wid  = threadIdx.x >> 6;
    const int m    = blockIdx.x * 4 + wid;

    const int segs = seg_start[m];
    const int sege = seg_start[m + 1];

    // max
    float lmax = -3.4e38f;
    for (int i = segs + lane; i < sege; i += 64) lmax = fmaxf(lmax, att[i]);
    const float bmax = wave_reduce_max(lmax);
    // sum
    float ls = 0.0f;
    for (int i = segs + lane; i < sege; i += 64) ls += __expf(att[i] - bmax);
    const float S   = wave_reduce_sum(ls);
    const float inv = 1.0f / (S + EPS_SM);
    if (lane == 0) wsum[m] = S * inv;

    // weighted accumulation — pure streaming FMA, no cross-lane ops
    float4 acc = make_float4(0.f, 0.f, 0.f, 0.f);
    for (int i = segs; i < sege; ++i) {
        const float w = __expf(att[i] - bmax) * inv;   // uniform broadcast
        float4 a = ((const float4*)(atom + (size_t)i * D_DIM))[lane];
        acc.x = fmaf(w, a.x, acc.x);
        acc.y = fmaf(w, a.y, acc.y);
        acc.z = fmaf(w, a.z, acc.z);
        acc.w = fmaf(w, a.w, acc.w);
        if (lane == 0) att[i] = w;                     // final weight
    }

    bf16x4 o;
    o[0] = (__bf16)acc.x; o[1] = (__bf16)acc.y; o[2] = (__bf16)acc.z; o[3] = (__bf16)acc.w;
    ((bf16x4*)ctxwn_bf)[(size_t)m * 64 + lane] = o;
}

// ---------------------------------------------------------------------------
// K2 (MFMA): context = elu( (ctxwn @ attend_w^T) * scale + wsum ⊗ cbias )
// ---------------------------------------------------------------------------
__global__ __launch_bounds__(256) void k2_context(
    const __bf16* __restrict__ A,    // ctxwn_bf [M,256]
    const __bf16* __restrict__ W,    // attend_w bf16 [256,256]
    const float* __restrict__ attend_b,
    const float* __restrict__ gamma_, const float* __restrict__ beta_,
    const float* __restrict__ mean_,  const float* __restrict__ var_,
    const float* __restrict__ wsum,
    __bf16* __restrict__ context_bf) // [M,256]
{
    const int tid  = threadIdx.x;
    const int wid  = tid >> 6;
    const int lane = tid & 63;
    const int quad = lane >> 4;
    const int r16  = lane & 15;
    const int m0   = blockIdx.x * 64;
    const int n0   = blockIdx.y * 64;

    const int arow = m0 + wid * 16 + r16;
    f32x4 acc[4] = {};

    #pragma unroll
    for (int ks = 0; ks < 8; ++ks) {
        const int ko = ks * 32 + quad * 8;
        bf16x8 af = *(const bf16x8*)&A[(size_t)arow * D_DIM + ko];
        #pragma unroll
        for (int t = 0; t < 4; ++t) {
            bf16x8 bf = *(const bf16x8*)&W[(size_t)(n0 + t * 16 + r16) * D_DIM + ko];
            acc[t] = __builtin_amdgcn_mfma_f32_16x16x32_bf16(af, bf, acc[t], 0, 0, 0);
        }
    }

    #pragma unroll
    for (int t = 0; t < 4; ++t) {
        const int col = n0 + t * 16 + r16;
        const float sc = gamma_[col] * rsqrtf(var_[col] + EPS_BN);
        const float cb = (attend_b[col] - mean_[col]) * sc + beta_[col];
        #pragma unroll
        for (int r = 0; r < 4; ++r) {
            const int row = m0 + wid * 16 + quad * 4 + r;
            float pre = acc[t][r] * sc + wsum[row] * cb;
            float e = pre > 0.0f ? pre : (__expf(pre) - 1.0f);
            context_bf[(size_t)row * D_DIM + col] = (__bf16)e;
        }
    }
}

// ---------------------------------------------------------------------------
// K3 (MFMA): fused GRU.
// ---------------------------------------------------------------------------
__global__ __launch_bounds__(256) void k3_gru(
    const __bf16* __restrict__ ctx_bf,  // [M,256]
    const __bf16* __restrict__ sup_bf,  // [M,256]
    const float*  __restrict__ superatom, // f32, exact h for the z-blend
    const __bf16* __restrict__ wih_bf,  // [768,256]
    const __bf16* __restrict__ whh_bf,  // [768,256]
    const float* __restrict__ bih,
    const float* __restrict__ bhh,
    float* __restrict__ out)            // [M,256]
{
    const int tid  = threadIdx.x;
    const int wid  = tid >> 6;
    const int lane = tid & 63;
    const int quad = lane >> 4;
    const int r16  = lane & 15;
    const int m0   = blockIdx.x * 64;
    const int n0   = blockIdx.y * 64;

    const int arow = m0 + wid * 16 + r16;
    f32x4 acc[6][4] = {};

    #pragma unroll
    for (int ks = 0; ks < 8; ++ks) {
        const int ko = ks * 32 + quad * 8;
        bf16x8 ca = *(const bf16x8*)&ctx_bf[(size_t)arow * D_DIM + ko];
        bf16x8 ha = *(const bf16x8*)&sup_bf[(size_t)arow * D_DIM + ko];
        #pragma unroll
        for (int t = 0; t < 4; ++t) {
            const int brow = n0 + t * 16 + r16;
            bf16x8 b0 = *(const bf16x8*)&wih_bf[(size_t)(0 * D_DIM + brow) * D_DIM + ko];
            bf16x8 b1 = *(const bf16x8*)&wih_bf[(size_t)(1 * D_DIM + brow) * D_DIM + ko];
            bf16x8 b2 = *(const bf16x8*)&wih_bf[(size_t)(2 * D_DIM + brow) * D_DIM + ko];
            bf16x8 b3 = *(const bf16x8*)&whh_bf[(size_t)(0 * D_DIM + brow) * D_DIM + ko];
            bf16x8 b4 = *(const bf16x8*)&whh_bf[(size_t)(1 * D_DIM + brow) * D_DIM + ko];
            bf16x8 b5 = *(const bf16x8*)&whh_bf[(size_t)(2 * D_DIM + brow) * D_DIM + ko];
            acc[0][t] = __builtin_amdgcn_mfma_f32_16x16x32_bf16(ca, b0, acc[0][t], 0, 0, 0);
            acc[1][t] = __builtin_amdgcn_mfma_f32_16x16x32_bf16(ca, b1, acc[1][t], 0, 0, 0);
            acc[2][t] = __builtin_amdgcn_mfma_f32_16x16x32_bf16(ca, b2, acc[2][t], 0, 0, 0);
            acc[3][t] = __builtin_amdgcn_mfma_f32_16x16x32_bf16(ha, b3, acc[3][t], 0, 0, 0);
            acc[4][t] = __builtin_amdgcn_mfma_f32_16x16x32_bf16(ha, b4, acc[4][t], 0, 0, 0);
            acc[5][t] = __builtin_amdgcn_mfma_f32_16x16x32_bf16(ha, b5, acc[5][t], 0, 0, 0);
        }
    }

    #pragma unroll
    for (int t = 0; t < 4; ++t) {
        const int col = n0 + t * 16 + r16;
        const float br  = bih[col]             + bhh[col];
        const float bz  = bih[D_DIM + col]     + bhh[D_DIM + col];
        const float bxn = bih[2 * D_DIM + col];
        const float bhn = bhh[2 * D_DIM + col];
        #pragma unroll
        for (int r = 0; r < 4; ++r) {
            const int row = m0 + wid * 16 + quad * 4 + r;
            float rg = sigmoidf_(acc[0][t][r] + acc[3][t][r] + br);
            float z  = sigmoidf_(acc[1][t][r] + acc[4][t][r] + bz);
            float n  = tanhf(acc[2][t][r] + bxn + rg * (acc[5][t][r] + bhn));
            float h  = superatom[(size_t)row * D_DIM + col];
            out[(size_t)row * D_DIM + col] = (1.0f - z) * n + z * h;
        }
    }
}

extern "C" void kernel_launch(void* const* d_in, const int* in_sizes, int n_in,
                              void* d_out, int out_size, void* d_ws, size_t ws_size,
                              hipStream_t stream) {
    const float* superatom = (const float*)d_in[0];
    const float* atom      = (const float*)d_in[1];
    const int*   mol_index = (const int*)d_in[2];
    const float* align_w   = (const float*)d_in[3];
    const float* align_b   = (const float*)d_in[4];
    const float* attend_w  = (const float*)d_in[5];
    const float* attend_b  = (const float*)d_in[6];
    const float* bn_gamma  = (const float*)d_in[7];
    const float* bn_beta   = (const float*)d_in[8];
    const float* bn_mean   = (const float*)d_in[9];
    const float* bn_var    = (const float*)d_in[10];
    const float* gru_wih   = (const float*)d_in[11];
    const float* gru_whh   = (const float*)d_in[12];
    const float* gru_bih   = (const float*)d_in[13];
    const float* gru_bhh   = (const float*)d_in[14];

    const int M = in_sizes[0] / D_DIM;
    const int N = in_sizes[2];

    float* out     = (float*)d_out;
    float* att_out = out + (size_t)M * D_DIM;   // attention weights [N]

    // workspace layout (16B-aligned chunks)
    char* ws = (char*)d_ws;
    __bf16* ctxwn_bf   = (__bf16*)ws;                     ws += (size_t)M * D_DIM * 2;
    __bf16* context_bf = (__bf16*)ws;                     ws += (size_t)M * D_DIM * 2;
    __bf16* sup_bf     = (__bf16*)ws;                     ws += (size_t)M * D_DIM * 2;
    __bf16* aw_bf      = (__bf16*)ws;                     ws += (size_t)D_DIM * D_DIM * 2;
    __bf16* wih_bf     = (__bf16*)ws;                     ws += (size_t)3 * D_DIM * D_DIM * 2;
    __bf16* whh_bf     = (__bf16*)ws;                     ws += (size_t)3 * D_DIM * D_DIM * 2;
    float*  wsum       = (float*)ws;                      ws += (size_t)M * 4;
    float*  cvec       = (float*)ws;                      ws += (size_t)M * 4;
    int*    seg_start  = (int*)ws;                        ws += (size_t)(M + 1) * 4;

    k0_convert<<<M / 4, 256, 0, stream>>>(superatom, sup_bf, M,
                                          align_w, align_b, cvec,
                                          attend_w, aw_bf, D_DIM * D_DIM,
                                          gru_wih, wih_bf, 3 * D_DIM * D_DIM,
                                          gru_whh, whh_bf, 3 * D_DIM * D_DIM);
    k1_score<<<2048, 256, 0, stream>>>(atom, mol_index, align_w, cvec,
                                       att_out, seg_start, N, M);
    k1_ctx<<<M / 4, 256, 0, stream>>>(atom, seg_start, att_out, ctxwn_bf, wsum);
    k2_context<<<dim3(M / 64, D_DIM / 64), 256, 0, stream>>>(ctxwn_bf, aw_bf, attend_b,
                                                             bn_gamma, bn_beta, bn_mean, bn_var,
                                                             wsum, context_bf);
    k3_gru<<<dim3(M / 64, D_DIM / 64), 256, 0, stream>>>(context_bf, sup_bf, superatom,
                                                         wih_bf, whh_bf, gru_bih, gru_bhh,
                                                         out);
}

// Round 2
// 823.084 us; speedup vs baseline: 1.1664x; 1.1664x over previous
//
#include <hip/hip_runtime.h>
#include <hip/hip_bf16.h>

#define D_DIM 256
#define EPS_BN 1e-6f
#define EPS_SM 1e-8f

typedef __bf16 bf16x8 __attribute__((ext_vector_type(8)));
typedef __bf16 bf16x4 __attribute__((ext_vector_type(4)));
typedef float  f32x4  __attribute__((ext_vector_type(4)));

__device__ __forceinline__ float wave_reduce_sum(float v) {
    #pragma unroll
    for (int off = 1; off < 64; off <<= 1) v += __shfl_xor(v, off);
    return v;
}

__device__ __forceinline__ float sigmoidf_(float x) {
    return 1.0f / (1.0f + __expf(-x));
}

__device__ __forceinline__ void cvt_region(const float* __restrict__ s,
                                           __bf16* __restrict__ d,
                                           int n4, int idx, int stride) {
    const float4* s4 = (const float4*)s;
    bf16x4* d4 = (bf16x4*)d;
    for (int i = idx; i < n4; i += stride) {
        float4 v = s4[i];
        bf16x4 o;
        o[0] = (__bf16)v.x; o[1] = (__bf16)v.y; o[2] = (__bf16)v.z; o[3] = (__bf16)v.w;
        d4[i] = o;
    }
}

// ---------------------------------------------------------------------------
// K0: bf16 conversions (weights + superatom), cvec[m] = dot(w1, superatom[m])+b,
// and segment-boundary scatter into seg_start[M+1] (one streaming read of
// mol_index; kills all binary searches in K1).
// ---------------------------------------------------------------------------
__global__ __launch_bounds__(256) void k0_convert(
    const float* __restrict__ superatom, __bf16* __restrict__ sup_bf, int M,
    const float* __restrict__ align_w,   const float* __restrict__ align_b,
    float* __restrict__ cvec,
    const int*   __restrict__ mol_index, int* __restrict__ seg_start, int N,
    const float* __restrict__ attend_w,  __bf16* __restrict__ aw_bf,  int n_aw,
    const float* __restrict__ wih,       __bf16* __restrict__ wih_bf, int n_wih,
    const float* __restrict__ whh,       __bf16* __restrict__ whh_bf, int n_whh)
{
    const int tid  = threadIdx.x;
    const int lane = tid & 63;
    const int gw   = (blockIdx.x * 256 + tid) >> 6;
    const int nw   = (gridDim.x * 256) >> 6;

    const float4 w1 = ((const float4*)align_w)[lane];
    const float  b0 = align_b[0];

    // superatom: convert + cvec in one read
    for (int m = gw; m < M; m += nw) {
        float4 s = ((const float4*)(superatom + (size_t)m * D_DIM))[lane];
        bf16x4 o;
        o[0] = (__bf16)s.x; o[1] = (__bf16)s.y; o[2] = (__bf16)s.z; o[3] = (__bf16)s.w;
        ((bf16x4*)sup_bf)[(size_t)m * 64 + lane] = o;
        float p = s.x * w1.x + s.y * w1.y + s.z * w1.z + s.w * w1.w;
        p = wave_reduce_sum(p);
        if (lane == 0) cvec[m] = p + b0;
    }

    const int idx    = blockIdx.x * 256 + tid;
    const int stride = gridDim.x * 256;
    cvt_region(attend_w, aw_bf,  n_aw / 4,  idx, stride);
    cvt_region(wih,      wih_bf, n_wih / 4, idx, stride);
    cvt_region(whh,      whh_bf, n_whh / 4, idx, stride);

    // segment boundaries
    for (int i = idx; i < N; i += stride) {
        const int m = mol_index[i];
        if (i == 0) {
            for (int mm = 0; mm <= m; ++mm) seg_start[mm] = 0;
        } else {
            const int mp = mol_index[i - 1];
            if (mp != m)
                for (int mm = mp + 1; mm <= m; ++mm) seg_start[mm] = i;
        }
        if (i == N - 1) {
            for (int mm = m + 1; mm <= M; ++mm) seg_start[mm] = N;
        }
    }
}

// ---------------------------------------------------------------------------
// K1: one block (4 waves) per molecule; segment bounds precomputed.
// SINGLE pass over atom rows with online softmax (running max/sum/weighted
// accumulator per wave, merged across waves at the end).
// att_out holds raw scores during the kernel, final weights at the end.
// ---------------------------------------------------------------------------
__global__ __launch_bounds__(256) void k1_segment(
    const float* __restrict__ atom,
    const float* __restrict__ align_w,
    const float* __restrict__ cvec,
    const int*   __restrict__ seg_start,
    __bf16* __restrict__ ctxwn_bf, // [M, D]
    float* __restrict__ wsum,      // [M]
    float* __restrict__ att_out,   // [N]
    int N)
{
    const int m    = blockIdx.x;
    const int tid  = threadIdx.x;
    const int wid  = tid >> 6;
    const int lane = tid & 63;

    const int segs = seg_start[m];
    const int sege = seg_start[m + 1];

    const float cm = cvec[m];
    const float4 wa = ((const float4*)(align_w + D_DIM))[lane];

    __shared__ float smax[4];
    __shared__ float ssum[4];
    __shared__ float sacc[4 * D_DIM];

    // ---- single pass: score + online softmax + weighted atom sum ----
    float m_run = -3.4e38f;
    float S = 0.0f;
    float4 acc = make_float4(0.f, 0.f, 0.f, 0.f);
    for (int i = segs + wid; i < sege; i += 4) {
        float4 a = ((const float4*)(atom + (size_t)i * D_DIM))[lane];
        float p = a.x * wa.x + a.y * wa.y + a.z * wa.z + a.w * wa.w;
        p = wave_reduce_sum(p);
        float sc = cm + p;
        sc = sc > 0.0f ? sc : 0.01f * sc;      // leaky_relu(0.01)
        if (lane == 0) att_out[i] = sc;        // stash raw score
        if (sc <= m_run) {                      // wave-uniform branch
            float e = __expf(sc - m_run);
            S += e;
            acc.x = fmaf(e, a.x, acc.x); acc.y = fmaf(e, a.y, acc.y);
            acc.z = fmaf(e, a.z, acc.z); acc.w = fmaf(e, a.w, acc.w);
        } else {
            float corr = __expf(m_run - sc);    // first iter: exp(-huge) = 0
            S = fmaf(S, corr, 1.0f);
            acc.x = fmaf(acc.x, corr, a.x); acc.y = fmaf(acc.y, corr, a.y);
            acc.z = fmaf(acc.z, corr, a.z); acc.w = fmaf(acc.w, corr, a.w);
            m_run = sc;
        }
    }
    if (lane == 0) smax[wid] = m_run;
    __syncthreads();
    const float bmax = fmaxf(fmaxf(smax[0], smax[1]), fmaxf(smax[2], smax[3]));
    // rescale wave-local state to the block max
    {
        float corr = __expf(m_run - bmax);      // 0 if this wave had no atoms
        S *= corr;
        acc.x *= corr; acc.y *= corr; acc.z *= corr; acc.w *= corr;
    }
    ((float4*)sacc)[wid * 64 + lane] = acc;
    if (lane == 0) ssum[wid] = S;
    __syncthreads();

    const float Stot = ssum[0] + ssum[1] + ssum[2] + ssum[3];
    const float inv  = 1.0f / (Stot + EPS_SM);
    float v = sacc[tid] + sacc[D_DIM + tid] + sacc[2 * D_DIM + tid] + sacc[3 * D_DIM + tid];
    ctxwn_bf[(size_t)m * D_DIM + tid] = (__bf16)(v * inv);
    if (tid == 0) wsum[m] = Stot * inv;

    // ---- final weights from stashed scores ----
    for (int i = segs + tid; i < sege; i += 256) {
        att_out[i] = __expf(att_out[i] - bmax) * inv;
    }
}

// ---------------------------------------------------------------------------
// K2 (MFMA): context = elu( (ctxwn @ attend_w^T) * scale + wsum ⊗ cbias )
// ---------------------------------------------------------------------------
__global__ __launch_bounds__(256) void k2_context(
    const __bf16* __restrict__ A,    // ctxwn_bf [M,256]
    const __bf16* __restrict__ W,    // attend_w bf16 [256,256]
    const float* __restrict__ attend_b,
    const float* __restrict__ gamma_, const float* __restrict__ beta_,
    const float* __restrict__ mean_,  const float* __restrict__ var_,
    const float* __restrict__ wsum,
    __bf16* __restrict__ context_bf) // [M,256]
{
    const int tid  = threadIdx.x;
    const int wid  = tid >> 6;
    const int lane = tid & 63;
    const int quad = lane >> 4;
    const int r16  = lane & 15;
    const int m0   = blockIdx.x * 64;
    const int n0   = blockIdx.y * 64;

    const int arow = m0 + wid * 16 + r16;
    f32x4 acc[4] = {};

    #pragma unroll
    for (int ks = 0; ks < 8; ++ks) {
        const int ko = ks * 32 + quad * 8;
        bf16x8 af = *(const bf16x8*)&A[(size_t)arow * D_DIM + ko];
        #pragma unroll
        for (int t = 0; t < 4; ++t) {
            bf16x8 bf = *(const bf16x8*)&W[(size_t)(n0 + t * 16 + r16) * D_DIM + ko];
            acc[t] = __builtin_amdgcn_mfma_f32_16x16x32_bf16(af, bf, acc[t], 0, 0, 0);
        }
    }

    #pragma unroll
    for (int t = 0; t < 4; ++t) {
        const int col = n0 + t * 16 + r16;
        const float sc = gamma_[col] * rsqrtf(var_[col] + EPS_BN);
        const float cb = (attend_b[col] - mean_[col]) * sc + beta_[col];
        #pragma unroll
        for (int r = 0; r < 4; ++r) {
            const int row = m0 + wid * 16 + quad * 4 + r;
            float pre = acc[t][r] * sc + wsum[row] * cb;
            float e = pre > 0.0f ? pre : (__expf(pre) - 1.0f);
            context_bf[(size_t)row * D_DIM + col] = (__bf16)e;
        }
    }
}

// ---------------------------------------------------------------------------
// K3 (MFMA): fused GRU.
// ---------------------------------------------------------------------------
__global__ __launch_bounds__(256) void k3_gru(
    const __bf16* __restrict__ ctx_bf,  // [M,256]
    const __bf16* __restrict__ sup_bf,  // [M,256]
    const float*  __restrict__ superatom, // f32, exact h for the z-blend
    const __bf16* __restrict__ wih_bf,  // [768,256]
    const __bf16* __restrict__ whh_bf,  // [768,256]
    const float* __restrict__ bih,
    const float* __restrict__ bhh,
    float* __restrict__ out)            // [M,256]
{
    const int tid  = threadIdx.x;
    const int wid  = tid >> 6;
    const int lane = tid & 63;
    const int quad = lane >> 4;
    const int r16  = lane & 15;
    const int m0   = blockIdx.x * 64;
    const int n0   = blockIdx.y * 64;

    const int arow = m0 + wid * 16 + r16;
    f32x4 acc[6][4] = {};

    #pragma unroll
    for (int ks = 0; ks < 8; ++ks) {
        const int ko = ks * 32 + quad * 8;
        bf16x8 ca = *(const bf16x8*)&ctx_bf[(size_t)arow * D_DIM + ko];
        bf16x8 ha = *(const bf16x8*)&sup_bf[(size_t)arow * D_DIM + ko];
        #pragma unroll
        for (int t = 0; t < 4; ++t) {
            const int brow = n0 + t * 16 + r16;
            bf16x8 b0 = *(const bf16x8*)&wih_bf[(size_t)(0 * D_DIM + brow) * D_DIM + ko];
            bf16x8 b1 = *(const bf16x8*)&wih_bf[(size_t)(1 * D_DIM + brow) * D_DIM + ko];
            bf16x8 b2 = *(const bf16x8*)&wih_bf[(size_t)(2 * D_DIM + brow) * D_DIM + ko];
            bf16x8 b3 = *(const bf16x8*)&whh_bf[(size_t)(0 * D_DIM + brow) * D_DIM + ko];
            bf16x8 b4 = *(const bf16x8*)&whh_bf[(size_t)(1 * D_DIM + brow) * D_DIM + ko];
            bf16x8 b5 = *(const bf16x8*)&whh_bf[(size_t)(2 * D_DIM + brow) * D_DIM + ko];
            acc[0][t] = __builtin_amdgcn_mfma_f32_16x16x32_bf16(ca, b0, acc[0][t], 0, 0, 0);
            acc[1][t] = __builtin_amdgcn_mfma_f32_16x16x32_bf16(ca, b1, acc[1][t], 0, 0, 0);
            acc[2][t] = __builtin_amdgcn_mfma_f32_16x16x32_bf16(ca, b2, acc[2][t], 0, 0, 0);
            acc[3][t] = __builtin_amdgcn_mfma_f32_16x16x32_bf16(ha, b3, acc[3][t], 0, 0, 0);
            acc[4][t] = __builtin_amdgcn_mfma_f32_16x16x32_bf16(ha, b4, acc[4][t], 0, 0, 0);
            acc[5][t] = __builtin_amdgcn_mfma_f32_16x16x32_bf16(ha, b5, acc[5][t], 0, 0, 0);
        }
    }

    #pragma unroll
    for (int t = 0; t < 4; ++t) {
        const int col = n0 + t * 16 + r16;
        const float br  = bih[col]             + bhh[col];
        const float bz  = bih[D_DIM + col]     + bhh[D_DIM + col];
        const float bxn = bih[2 * D_DIM + col];
        const float bhn = bhh[2 * D_DIM + col];
        #pragma unroll
        for (int r = 0; r < 4; ++r) {
            const int row = m0 + wid * 16 + quad * 4 + r;
            float rg = sigmoidf_(acc[0][t][r] + acc[3][t][r] + br);
            float z  = sigmoidf_(acc[1][t][r] + acc[4][t][r] + bz);
            float n  = tanhf(acc[2][t][r] + bxn + rg * (acc[5][t][r] + bhn));
            float h  = superatom[(size_t)row * D_DIM + col];
            out[(size_t)row * D_DIM + col] = (1.0f - z) * n + z * h;
        }
    }
}

extern "C" void kernel_launch(void* const* d_in, const int* in_sizes, int n_in,
                              void* d_out, int out_size, void* d_ws, size_t ws_size,
                              hipStream_t stream) {
    const float* superatom = (const float*)d_in[0];
    const float* atom      = (const float*)d_in[1];
    const int*   mol_index = (const int*)d_in[2];
    const float* align_w   = (const float*)d_in[3];
    const float* align_b   = (const float*)d_in[4];
    const float* attend_w  = (const float*)d_in[5];
    const float* attend_b  = (const float*)d_in[6];
    const float* bn_gamma  = (const float*)d_in[7];
    const float* bn_beta   = (const float*)d_in[8];
    const float* bn_mean   = (const float*)d_in[9];
    const float* bn_var    = (const float*)d_in[10];
    const float* gru_wih   = (const float*)d_in[11];
    const float* gru_whh   = (const float*)d_in[12];
    const float* gru_bih   = (const float*)d_in[13];
    const float* gru_bhh   = (const float*)d_in[14];

    const int M = in_sizes[0] / D_DIM;
    const int N = in_sizes[2];

    float* out     = (float*)d_out;
    float* att_out = out + (size_t)M * D_DIM;   // attention weights [N]

    // workspace layout (16B-aligned chunks)
    char* ws = (char*)d_ws;
    __bf16* ctxwn_bf   = (__bf16*)ws;                     ws += (size_t)M * D_DIM * 2;
    __bf16* context_bf = (__bf16*)ws;                     ws += (size_t)M * D_DIM * 2;
    __bf16* sup_bf     = (__bf16*)ws;                     ws += (size_t)M * D_DIM * 2;
    __bf16* aw_bf      = (__bf16*)ws;                     ws += (size_t)D_DIM * D_DIM * 2;
    __bf16* wih_bf     = (__bf16*)ws;                     ws += (size_t)3 * D_DIM * D_DIM * 2;
    __bf16* whh_bf     = (__bf16*)ws;                     ws += (size_t)3 * D_DIM * D_DIM * 2;
    float*  wsum       = (float*)ws;                      ws += (size_t)M * 4;
    float*  cvec       = (float*)ws;                      ws += (size_t)M * 4;
    int*    seg_start  = (int*)ws;                        ws += (size_t)(M + 1) * 4;

    k0_convert<<<M / 4, 256, 0, stream>>>(superatom, sup_bf, M,
                                          align_w, align_b, cvec,
                                          mol_index, seg_start, N,
                                          attend_w, aw_bf, D_DIM * D_DIM,
                                          gru_wih, wih_bf, 3 * D_DIM * D_DIM,
                                          gru_whh, whh_bf, 3 * D_DIM * D_DIM);
    k1_segment<<<M, 256, 0, stream>>>(atom, align_w, cvec, seg_start,
                                      ctxwn_bf, wsum, att_out, N);
    k2_context<<<dim3(M / 64, D_DIM / 64), 256, 0, stream>>>(ctxwn_bf, aw_bf, attend_b,
                                                             bn_gamma, bn_beta, bn_mean, bn_var,
                                                             wsum, context_bf);
    k3_gru<<<dim3(M / 64, D_DIM / 64), 256, 0, stream>>>(context_bf, sup_bf, superatom,
                                                         wih_bf, whh_bf, gru_bih, gru_bhh,
                                                         out);
}

// Round 3
// 816.936 us; speedup vs baseline: 1.1751x; 1.0075x over previous
//
#include <hip/hip_runtime.h>
#include <hip/hip_bf16.h>

#define D_DIM 256
#define EPS_BN 1e-6f
#define EPS_SM 1e-8f

typedef __bf16 bf16x8 __attribute__((ext_vector_type(8)));
typedef __bf16 bf16x4 __attribute__((ext_vector_type(4)));
typedef float  f32x4  __attribute__((ext_vector_type(4)));

__device__ __forceinline__ float wave_reduce_sum(float v) {
    #pragma unroll
    for (int off = 1; off < 64; off <<= 1) v += __shfl_xor(v, off);
    return v;
}

__device__ __forceinline__ float sigmoidf_(float x) {
    return 1.0f / (1.0f + __expf(-x));
}

__device__ __forceinline__ void cvt_region(const float* __restrict__ s,
                                           __bf16* __restrict__ d,
                                           int n4, int idx, int stride) {
    const float4* s4 = (const float4*)s;
    bf16x4* d4 = (bf16x4*)d;
    for (int i = idx; i < n4; i += stride) {
        float4 v = s4[i];
        bf16x4 o;
        o[0] = (__bf16)v.x; o[1] = (__bf16)v.y; o[2] = (__bf16)v.z; o[3] = (__bf16)v.w;
        d4[i] = o;
    }
}

// ---------------------------------------------------------------------------
// K0: weight bf16 conversions, cvec[m] = dot(w1, superatom[m]) + b, and
// segment-boundary scatter into seg_start[M+1].
// ---------------------------------------------------------------------------
__global__ __launch_bounds__(256) void k0_convert(
    const float* __restrict__ superatom, int M,
    const float* __restrict__ align_w,   const float* __restrict__ align_b,
    float* __restrict__ cvec,
    const int*   __restrict__ mol_index, int* __restrict__ seg_start, int N,
    const float* __restrict__ attend_w,  __bf16* __restrict__ aw_bf,  int n_aw,
    const float* __restrict__ wih,       __bf16* __restrict__ wih_bf, int n_wih,
    const float* __restrict__ whh,       __bf16* __restrict__ whh_bf, int n_whh)
{
    const int tid  = threadIdx.x;
    const int lane = tid & 63;
    const int gw   = (blockIdx.x * 256 + tid) >> 6;
    const int nw   = (gridDim.x * 256) >> 6;

    const float4 w1 = ((const float4*)align_w)[lane];
    const float  b0 = align_b[0];

    // cvec from superatom
    for (int m = gw; m < M; m += nw) {
        float4 s = ((const float4*)(superatom + (size_t)m * D_DIM))[lane];
        float p = s.x * w1.x + s.y * w1.y + s.z * w1.z + s.w * w1.w;
        p = wave_reduce_sum(p);
        if (lane == 0) cvec[m] = p + b0;
    }

    const int idx    = blockIdx.x * 256 + tid;
    const int stride = gridDim.x * 256;
    cvt_region(attend_w, aw_bf,  n_aw / 4,  idx, stride);
    cvt_region(wih,      wih_bf, n_wih / 4, idx, stride);
    cvt_region(whh,      whh_bf, n_whh / 4, idx, stride);

    // segment boundaries
    for (int i = idx; i < N; i += stride) {
        const int m = mol_index[i];
        if (i == 0) {
            for (int mm = 0; mm <= m; ++mm) seg_start[mm] = 0;
        } else {
            const int mp = mol_index[i - 1];
            if (mp != m)
                for (int mm = mp + 1; mm <= m; ++mm) seg_start[mm] = i;
        }
        if (i == N - 1) {
            for (int mm = m + 1; mm <= M; ++mm) seg_start[mm] = N;
        }
    }
}

// ---------------------------------------------------------------------------
// K1: one block (4 waves) per molecule; segment bounds precomputed.
// SINGLE pass over atom rows with online softmax.
// ---------------------------------------------------------------------------
__global__ __launch_bounds__(256) void k1_segment(
    const float* __restrict__ atom,
    const float* __restrict__ align_w,
    const float* __restrict__ cvec,
    const int*   __restrict__ seg_start,
    __bf16* __restrict__ ctxwn_bf, // [M, D]
    float* __restrict__ wsum,      // [M]
    float* __restrict__ att_out,   // [N]
    int N)
{
    const int m    = blockIdx.x;
    const int tid  = threadIdx.x;
    const int wid  = tid >> 6;
    const int lane = tid & 63;

    const int segs = seg_start[m];
    const int sege = seg_start[m + 1];

    const float cm = cvec[m];
    const float4 wa = ((const float4*)(align_w + D_DIM))[lane];

    __shared__ float smax[4];
    __shared__ float ssum[4];
    __shared__ float sacc[4 * D_DIM];

    float m_run = -3.4e38f;
    float S = 0.0f;
    float4 acc = make_float4(0.f, 0.f, 0.f, 0.f);
    for (int i = segs + wid; i < sege; i += 4) {
        float4 a = ((const float4*)(atom + (size_t)i * D_DIM))[lane];
        float p = a.x * wa.x + a.y * wa.y + a.z * wa.z + a.w * wa.w;
        p = wave_reduce_sum(p);
        float sc = cm + p;
        sc = sc > 0.0f ? sc : 0.01f * sc;      // leaky_relu(0.01)
        if (lane == 0) att_out[i] = sc;        // stash raw score
        if (sc <= m_run) {                      // wave-uniform branch
            float e = __expf(sc - m_run);
            S += e;
            acc.x = fmaf(e, a.x, acc.x); acc.y = fmaf(e, a.y, acc.y);
            acc.z = fmaf(e, a.z, acc.z); acc.w = fmaf(e, a.w, acc.w);
        } else {
            float corr = __expf(m_run - sc);    // first iter: exp(-huge) = 0
            S = fmaf(S, corr, 1.0f);
            acc.x = fmaf(acc.x, corr, a.x); acc.y = fmaf(acc.y, corr, a.y);
            acc.z = fmaf(acc.z, corr, a.z); acc.w = fmaf(acc.w, corr, a.w);
            m_run = sc;
        }
    }
    if (lane == 0) smax[wid] = m_run;
    __syncthreads();
    const float bmax = fmaxf(fmaxf(smax[0], smax[1]), fmaxf(smax[2], smax[3]));
    {
        float corr = __expf(m_run - bmax);      // 0 if this wave had no atoms
        S *= corr;
        acc.x *= corr; acc.y *= corr; acc.z *= corr; acc.w *= corr;
    }
    ((float4*)sacc)[wid * 64 + lane] = acc;
    if (lane == 0) ssum[wid] = S;
    __syncthreads();

    const float Stot = ssum[0] + ssum[1] + ssum[2] + ssum[3];
    const float inv  = 1.0f / (Stot + EPS_SM);
    float v = sacc[tid] + sacc[D_DIM + tid] + sacc[2 * D_DIM + tid] + sacc[3 * D_DIM + tid];
    ctxwn_bf[(size_t)m * D_DIM + tid] = (__bf16)(v * inv);
    if (tid == 0) wsum[m] = Stot * inv;

    for (int i = segs + tid; i < sege; i += 256) {
        att_out[i] = __expf(att_out[i] - bmax) * inv;
    }
}

// ---------------------------------------------------------------------------
// K2 (MFMA): context = elu( (ctxwn @ attend_w^T) * scale + wsum ⊗ cbias )
// 32 rows per wave (2 row-groups of 16): each B-frag feeds 2 MFMAs.
// Grid (M/128, D/64), 4 waves.
// ---------------------------------------------------------------------------
__global__ __launch_bounds__(256) void k2_context(
    const __bf16* __restrict__ A,    // ctxwn_bf [M,256]
    const __bf16* __restrict__ W,    // attend_w bf16 [256,256]
    const float* __restrict__ attend_b,
    const float* __restrict__ gamma_, const float* __restrict__ beta_,
    const float* __restrict__ mean_,  const float* __restrict__ var_,
    const float* __restrict__ wsum,
    __bf16* __restrict__ context_bf) // [M,256]
{
    const int tid  = threadIdx.x;
    const int wid  = tid >> 6;
    const int lane = tid & 63;
    const int quad = lane >> 4;
    const int r16  = lane & 15;
    const int m0   = blockIdx.x * 128;
    const int n0   = blockIdx.y * 64;

    const int rowbase = m0 + wid * 32;
    const int arow0 = rowbase + r16;
    const int arow1 = rowbase + 16 + r16;
    f32x4 acc[2][4] = {};

    #pragma unroll
    for (int ks = 0; ks < 8; ++ks) {
        const int ko = ks * 32 + quad * 8;
        bf16x8 af0 = *(const bf16x8*)&A[(size_t)arow0 * D_DIM + ko];
        bf16x8 af1 = *(const bf16x8*)&A[(size_t)arow1 * D_DIM + ko];
        #pragma unroll
        for (int t = 0; t < 4; ++t) {
            bf16x8 bfw = *(const bf16x8*)&W[(size_t)(n0 + t * 16 + r16) * D_DIM + ko];
            acc[0][t] = __builtin_amdgcn_mfma_f32_16x16x32_bf16(af0, bfw, acc[0][t], 0, 0, 0);
            acc[1][t] = __builtin_amdgcn_mfma_f32_16x16x32_bf16(af1, bfw, acc[1][t], 0, 0, 0);
        }
    }

    #pragma unroll
    for (int t = 0; t < 4; ++t) {
        const int col = n0 + t * 16 + r16;
        const float sc = gamma_[col] * rsqrtf(var_[col] + EPS_BN);
        const float cb = (attend_b[col] - mean_[col]) * sc + beta_[col];
        #pragma unroll
        for (int g = 0; g < 2; ++g) {
            #pragma unroll
            for (int r = 0; r < 4; ++r) {
                const int row = rowbase + g * 16 + quad * 4 + r;
                float pre = acc[g][t][r] * sc + wsum[row] * cb;
                float e = pre > 0.0f ? pre : (__expf(pre) - 1.0f);
                context_bf[(size_t)row * D_DIM + col] = (__bf16)e;
            }
        }
    }
}

// ---------------------------------------------------------------------------
// K3 (MFMA): fused GRU. 32 rows per wave (2 row-groups): halves B-frag L2
// traffic vs 16-row version. h-frags built from f32 superatom on the fly
// (same bf16 quantization as before); epilogue superatom reads hit L2.
// Grid (M/128, D/64), 4 waves, launch_bounds(256,1) for VGPR headroom.
// ---------------------------------------------------------------------------
__global__ __launch_bounds__(256, 1) void k3_gru(
    const __bf16* __restrict__ ctx_bf,    // [M,256]
    const float*  __restrict__ superatom, // f32 [M,256]
    const __bf16* __restrict__ wih_bf,    // [768,256]
    const __bf16* __restrict__ whh_bf,    // [768,256]
    const float* __restrict__ bih,
    const float* __restrict__ bhh,
    float* __restrict__ out)              // [M,256]
{
    const int tid  = threadIdx.x;
    const int wid  = tid >> 6;
    const int lane = tid & 63;
    const int quad = lane >> 4;
    const int r16  = lane & 15;
    const int m0   = blockIdx.x * 128;
    const int n0   = blockIdx.y * 64;

    const int rowbase = m0 + wid * 32;
    const int arow0 = rowbase + r16;
    const int arow1 = rowbase + 16 + r16;

    f32x4 acc[6][4][2] = {};   // [matrix][t][row-group]

    #pragma unroll
    for (int ks = 0; ks < 8; ++ks) {
        const int ko = ks * 32 + quad * 8;
        bf16x8 ca0 = *(const bf16x8*)&ctx_bf[(size_t)arow0 * D_DIM + ko];
        bf16x8 ca1 = *(const bf16x8*)&ctx_bf[(size_t)arow1 * D_DIM + ko];
        // h frags from f32 superatom (round-to-nearest-even bf16, as before)
        float4 h0a = *(const float4*)&superatom[(size_t)arow0 * D_DIM + ko];
        float4 h0b = *(const float4*)&superatom[(size_t)arow0 * D_DIM + ko + 4];
        float4 h1a = *(const float4*)&superatom[(size_t)arow1 * D_DIM + ko];
        float4 h1b = *(const float4*)&superatom[(size_t)arow1 * D_DIM + ko + 4];
        bf16x8 ha0, ha1;
        ha0[0] = (__bf16)h0a.x; ha0[1] = (__bf16)h0a.y; ha0[2] = (__bf16)h0a.z; ha0[3] = (__bf16)h0a.w;
        ha0[4] = (__bf16)h0b.x; ha0[5] = (__bf16)h0b.y; ha0[6] = (__bf16)h0b.z; ha0[7] = (__bf16)h0b.w;
        ha1[0] = (__bf16)h1a.x; ha1[1] = (__bf16)h1a.y; ha1[2] = (__bf16)h1a.z; ha1[3] = (__bf16)h1a.w;
        ha1[4] = (__bf16)h1b.x; ha1[5] = (__bf16)h1b.y; ha1[6] = (__bf16)h1b.z; ha1[7] = (__bf16)h1b.w;

        #pragma unroll
        for (int t = 0; t < 4; ++t) {
            const int brow = n0 + t * 16 + r16;
            bf16x8 b0 = *(const bf16x8*)&wih_bf[(size_t)(0 * D_DIM + brow) * D_DIM + ko];
            bf16x8 b1 = *(const bf16x8*)&wih_bf[(size_t)(1 * D_DIM + brow) * D_DIM + ko];
            bf16x8 b2 = *(const bf16x8*)&wih_bf[(size_t)(2 * D_DIM + brow) * D_DIM + ko];
            bf16x8 b3 = *(const bf16x8*)&whh_bf[(size_t)(0 * D_DIM + brow) * D_DIM + ko];
            bf16x8 b4 = *(const bf16x8*)&whh_bf[(size_t)(1 * D_DIM + brow) * D_DIM + ko];
            bf16x8 b5 = *(const bf16x8*)&whh_bf[(size_t)(2 * D_DIM + brow) * D_DIM + ko];
            acc[0][t][0] = __builtin_amdgcn_mfma_f32_16x16x32_bf16(ca0, b0, acc[0][t][0], 0, 0, 0);
            acc[0][t][1] = __builtin_amdgcn_mfma_f32_16x16x32_bf16(ca1, b0, acc[0][t][1], 0, 0, 0);
            acc[1][t][0] = __builtin_amdgcn_mfma_f32_16x16x32_bf16(ca0, b1, acc[1][t][0], 0, 0, 0);
            acc[1][t][1] = __builtin_amdgcn_mfma_f32_16x16x32_bf16(ca1, b1, acc[1][t][1], 0, 0, 0);
            acc[2][t][0] = __builtin_amdgcn_mfma_f32_16x16x32_bf16(ca0, b2, acc[2][t][0], 0, 0, 0);
            acc[2][t][1] = __builtin_amdgcn_mfma_f32_16x16x32_bf16(ca1, b2, acc[2][t][1], 0, 0, 0);
            acc[3][t][0] = __builtin_amdgcn_mfma_f32_16x16x32_bf16(ha0, b3, acc[3][t][0], 0, 0, 0);
            acc[3][t][1] = __builtin_amdgcn_mfma_f32_16x16x32_bf16(ha1, b3, acc[3][t][1], 0, 0, 0);
            acc[4][t][0] = __builtin_amdgcn_mfma_f32_16x16x32_bf16(ha0, b4, acc[4][t][0], 0, 0, 0);
            acc[4][t][1] = __builtin_amdgcn_mfma_f32_16x16x32_bf16(ha1, b4, acc[4][t][1], 0, 0, 0);
            acc[5][t][0] = __builtin_amdgcn_mfma_f32_16x16x32_bf16(ha0, b5, acc[5][t][0], 0, 0, 0);
            acc[5][t][1] = __builtin_amdgcn_mfma_f32_16x16x32_bf16(ha1, b5, acc[5][t][1], 0, 0, 0);
        }
    }

    #pragma unroll
    for (int t = 0; t < 4; ++t) {
        const int col = n0 + t * 16 + r16;
        const float br  = bih[col]             + bhh[col];
        const float bz  = bih[D_DIM + col]     + bhh[D_DIM + col];
        const float bxn = bih[2 * D_DIM + col];
        const float bhn = bhh[2 * D_DIM + col];
        #pragma unroll
        for (int g = 0; g < 2; ++g) {
            #pragma unroll
            for (int r = 0; r < 4; ++r) {
                const int row = rowbase + g * 16 + quad * 4 + r;
                float rg = sigmoidf_(acc[0][t][g][r] + acc[3][t][g][r] + br);
                float z  = sigmoidf_(acc[1][t][g][r] + acc[4][t][g][r] + bz);
                float n  = tanhf(acc[2][t][g][r] + bxn + rg * (acc[5][t][g][r] + bhn));
                float h  = superatom[(size_t)row * D_DIM + col];
                out[(size_t)row * D_DIM + col] = (1.0f - z) * n + z * h;
            }
        }
    }
}

extern "C" void kernel_launch(void* const* d_in, const int* in_sizes, int n_in,
                              void* d_out, int out_size, void* d_ws, size_t ws_size,
                              hipStream_t stream) {
    const float* superatom = (const float*)d_in[0];
    const float* atom      = (const float*)d_in[1];
    const int*   mol_index = (const int*)d_in[2];
    const float* align_w   = (const float*)d_in[3];
    const float* align_b   = (const float*)d_in[4];
    const float* attend_w  = (const float*)d_in[5];
    const float* attend_b  = (const float*)d_in[6];
    const float* bn_gamma  = (const float*)d_in[7];
    const float* bn_beta   = (const float*)d_in[8];
    const float* bn_mean   = (const float*)d_in[9];
    const float* bn_var    = (const float*)d_in[10];
    const float* gru_wih   = (const float*)d_in[11];
    const float* gru_whh   = (const float*)d_in[12];
    const float* gru_bih   = (const float*)d_in[13];
    const float* gru_bhh   = (const float*)d_in[14];

    const int M = in_sizes[0] / D_DIM;
    const int N = in_sizes[2];

    float* out     = (float*)d_out;
    float* att_out = out + (size_t)M * D_DIM;   // attention weights [N]

    // workspace layout (16B-aligned chunks)
    char* ws = (char*)d_ws;
    __bf16* ctxwn_bf   = (__bf16*)ws;                     ws += (size_t)M * D_DIM * 2;
    __bf16* context_bf = (__bf16*)ws;                     ws += (size_t)M * D_DIM * 2;
    __bf16* aw_bf      = (__bf16*)ws;                     ws += (size_t)D_DIM * D_DIM * 2;
    __bf16* wih_bf     = (__bf16*)ws;                     ws += (size_t)3 * D_DIM * D_DIM * 2;
    __bf16* whh_bf     = (__bf16*)ws;                     ws += (size_t)3 * D_DIM * D_DIM * 2;
    float*  wsum       = (float*)ws;                      ws += (size_t)M * 4;
    float*  cvec       = (float*)ws;                      ws += (size_t)M * 4;
    int*    seg_start  = (int*)ws;                        ws += (size_t)(M + 1) * 4;

    k0_convert<<<M / 4, 256, 0, stream>>>(superatom, M,
                                          align_w, align_b, cvec,
                                          mol_index, seg_start, N,
                                          attend_w, aw_bf, D_DIM * D_DIM,
                                          gru_wih, wih_bf, 3 * D_DIM * D_DIM,
                                          gru_whh, whh_bf, 3 * D_DIM * D_DIM);
    k1_segment<<<M, 256, 0, stream>>>(atom, align_w, cvec, seg_start,
                                      ctxwn_bf, wsum, att_out, N);
    k2_context<<<dim3(M / 128, D_DIM / 64), 256, 0, stream>>>(ctxwn_bf, aw_bf, attend_b,
                                                              bn_gamma, bn_beta, bn_mean, bn_var,
                                                              wsum, context_bf);
    k3_gru<<<dim3(M / 128, D_DIM / 64), 256, 0, stream>>>(context_bf, superatom,
                                                          wih_bf, whh_bf, gru_bih, gru_bhh,
                                                          out);
}